// Round 1
// baseline (901.769 us; speedup 1.0000x reference)
//
#include <hip/hip_runtime.h>
#include <hip/hip_bf16.h>

// CellSmooth: scores = q_j - ||enc_i - enc_j||; out = softmax(scores) @ expression
// N=8192, G=2048, D=64.  Single fused flash-style kernel: per (128-row x 256-col)
// block, loop all j in steps of 64: S-tile via 16x16x32 bf16 MFMA, p=exp(s)
// (no max shift needed: s in [-21, 4.3]), accumulate l inline, PV via 32x32x16
// bf16 MFMA with P routed through LDS.  Diagonal forced to d=0 (bf16 cancellation
// there would cost ~20% of the dominant softmax weight otherwise).

typedef __attribute__((ext_vector_type(8))) short bf16x8;
typedef __attribute__((ext_vector_type(4))) float f32x4;
typedef __attribute__((ext_vector_type(16))) float f32x16;

constexpr int N_ = 8192;
constexpr int G_ = 2048;
constexpr int D_ = 64;

__device__ __forceinline__ unsigned short f32_to_bf16(float f) {
  unsigned u = __builtin_bit_cast(unsigned, f);
  u = (u + 0x7FFFu + ((u >> 16) & 1u)) >> 16;  // RTNE
  return (unsigned short)u;
}
__device__ __forceinline__ float bf16_to_f32(unsigned short h) {
  unsigned u = ((unsigned)h) << 16;
  return __builtin_bit_cast(float, u);
}

// --- kernel 1: row norms + packed (norm, quality) + enc -> bf16 ---
__global__ void prep_kernel(const float* __restrict__ enc,
                            const float* __restrict__ quality,
                            float* __restrict__ norms,
                            float2* __restrict__ nq,
                            unsigned short* __restrict__ encb) {
  int row = blockIdx.x * blockDim.x + threadIdx.x;
  if (row >= N_) return;
  const float* r = enc + (size_t)row * D_;
  float n = 0.f;
#pragma unroll
  for (int k = 0; k < D_; k += 4) {
    float4 v = *(const float4*)(r + k);
    n += v.x * v.x + v.y * v.y + v.z * v.z + v.w * v.w;
    ushort4 h;
    h.x = f32_to_bf16(v.x); h.y = f32_to_bf16(v.y);
    h.z = f32_to_bf16(v.z); h.w = f32_to_bf16(v.w);
    *(ushort4*)(encb + (size_t)row * D_ + k) = h;
  }
  norms[row] = n;
  nq[row] = make_float2(n, quality[row]);
}

// --- kernel 2: expression [N][G] f32 -> ET [G][N] bf16 (transpose+convert) ---
__global__ void etrans_kernel(const float* __restrict__ E,
                              unsigned short* __restrict__ ET) {
  __shared__ __align__(16) unsigned short t[64 * 72];  // [g][j] padded
  int j0 = blockIdx.x * 64;
  int g0 = blockIdx.y * 64;
  int tid = threadIdx.x;
#pragma unroll
  for (int it = 0; it < 4; ++it) {
    int r = it * 16 + (tid >> 4);   // j local
    int c4 = tid & 15;              // g segment of 4
    float4 v = *(const float4*)(E + (size_t)(j0 + r) * G_ + g0 + c4 * 4);
    t[(c4 * 4 + 0) * 72 + r] = f32_to_bf16(v.x);
    t[(c4 * 4 + 1) * 72 + r] = f32_to_bf16(v.y);
    t[(c4 * 4 + 2) * 72 + r] = f32_to_bf16(v.z);
    t[(c4 * 4 + 3) * 72 + r] = f32_to_bf16(v.w);
  }
  __syncthreads();
#pragma unroll
  for (int it = 0; it < 2; ++it) {
    int g = it * 32 + (tid >> 3);
    int ch = tid & 7;
    bf16x8 v = *(const bf16x8*)(&t[g * 72 + ch * 8]);  // g*144 B, 16B aligned
    *(bf16x8*)(ET + (size_t)(g0 + g) * N_ + j0 + ch * 8) = v;
  }
}

// --- kernel 3: fused distance-softmax-matmul ---
// block: 128 i-rows x 256 g-cols, 256 threads (4 waves).
// wave w: S rows [32w,32w+32); PV quadrant (wr=w>>1 rows 64, wc=w&1 cols 128).
__global__ __launch_bounds__(256, 2)
void fused_kernel(const unsigned short* __restrict__ encb,  // [N][64] bf16
                  const float* __restrict__ norms,          // [N]
                  const float2* __restrict__ nq,            // [N] {norm, quality}
                  const unsigned short* __restrict__ ET,    // [G][N] bf16
                  float* __restrict__ out) {                // [N][G] f32
  __shared__ __align__(16) unsigned short p_lds[128 * 72];  // [i][j] pad 72
  __shared__ __align__(16) unsigned short e_lds[256 * 72];  // [g][j] pad 72
  __shared__ float linv_lds[128];

  const int tid = threadIdx.x;
  const int wave = tid >> 6;
  const int lane = tid & 63;
  const int quad = lane >> 4;   // 16x16 MFMA
  const int l15 = lane & 15;
  const int half = lane >> 5;   // 32x32 MFMA
  const int l31 = lane & 31;

  const int gt = blockIdx.x & 7;
  const int it = blockIdx.x >> 3;
  const int i0 = it * 128;
  const int g0 = gt * 256;

  const int srow = 32 * wave;
  const int wr = wave >> 1, wc = wave & 1;
  const int prow = 64 * wr;
  const int pcol = 128 * wc;

  // preload S A-frags (enc rows of my i-slice): A[m=l15][k=quad*8+j]
  bf16x8 afrag[2][2];
#pragma unroll
  for (int rt = 0; rt < 2; ++rt)
#pragma unroll
    for (int ks = 0; ks < 2; ++ks)
      afrag[rt][ks] = *(const bf16x8*)(encb +
          (size_t)(i0 + srow + rt * 16 + l15) * 64 + ks * 32 + quad * 8);

  // norms for my S rows (C-layout rows quad*4+r)
  float ni[2][4];
#pragma unroll
  for (int rt = 0; rt < 2; ++rt)
#pragma unroll
    for (int r = 0; r < 4; ++r)
      ni[rt][r] = norms[i0 + srow + rt * 16 + quad * 4 + r];

  float lsum[2][4] = {};
  f32x16 acc[2][4];
#pragma unroll
  for (int a = 0; a < 2; ++a)
#pragma unroll
    for (int b = 0; b < 4; ++b)
#pragma unroll
      for (int e = 0; e < 16; ++e) acc[a][b][e] = 0.f;

  for (int j0j = 0; j0j < N_; j0j += 64) {
    // stage ET tile: 256 g x 64 j into LDS (padded)
#pragma unroll
    for (int s = 0; s < 8; ++s) {
      int g = s * 32 + (tid >> 3);
      int ch = tid & 7;
      bf16x8 v = *(const bf16x8*)(ET + (size_t)(g0 + g) * N_ + j0j + ch * 8);
      *(bf16x8*)(&e_lds[g * 72 + ch * 8]) = v;
    }
    // S tile rows [srow, srow+32) x 64 j
#pragma unroll
    for (int jt = 0; jt < 4; ++jt) {
      const int jrow = j0j + jt * 16 + l15;  // B[n=l15][k=quad*8+j] = enc[jrow][k]
      bf16x8 b0 = *(const bf16x8*)(encb + (size_t)jrow * 64 + quad * 8);
      bf16x8 b1 = *(const bf16x8*)(encb + (size_t)jrow * 64 + 32 + quad * 8);
      float2 njq = nq[jrow];
#pragma unroll
      for (int rt = 0; rt < 2; ++rt) {
        f32x4 s4 = {0.f, 0.f, 0.f, 0.f};
        s4 = __builtin_amdgcn_mfma_f32_16x16x32_bf16(afrag[rt][0], b0, s4, 0, 0, 0);
        s4 = __builtin_amdgcn_mfma_f32_16x16x32_bf16(afrag[rt][1], b1, s4, 0, 0, 0);
#pragma unroll
        for (int r = 0; r < 4; ++r) {
          int i_loc = srow + rt * 16 + quad * 4 + r;  // C/D: row=quad*4+r, col=l15
          float d2 = fmaxf(ni[rt][r] + njq.x - 2.0f * s4[r], 0.f);
          float sc = njq.y - sqrtf(d2);
          if (i0 + i_loc == jrow) sc = njq.y;  // exact diagonal: d=0
          float p = __expf(sc);                 // s in [-21, ~4.3]: no max shift
          unsigned short pb = f32_to_bf16(p);
          lsum[rt][r] += bf16_to_f32(pb);       // l from the rounded p: consistent
          p_lds[i_loc * 72 + jt * 16 + l15] = pb;
        }
      }
    }
    __syncthreads();
    // PV: 32x32x16, A[m=l31][k=half*8+j], B[k=half*8+j][n=l31]
#pragma unroll
    for (int ks = 0; ks < 4; ++ks) {
      bf16x8 pa0 = *(const bf16x8*)(&p_lds[(prow + l31) * 72 + ks * 16 + half * 8]);
      bf16x8 pa1 = *(const bf16x8*)(&p_lds[(prow + 32 + l31) * 72 + ks * 16 + half * 8]);
#pragma unroll
      for (int ct = 0; ct < 4; ++ct) {
        bf16x8 eb = *(const bf16x8*)(&e_lds[(pcol + ct * 32 + l31) * 72 + ks * 16 + half * 8]);
        acc[0][ct] = __builtin_amdgcn_mfma_f32_32x32x16_bf16(pa0, eb, acc[0][ct], 0, 0, 0);
        acc[1][ct] = __builtin_amdgcn_mfma_f32_32x32x16_bf16(pa1, eb, acc[1][ct], 0, 0, 0);
      }
    }
    __syncthreads();
  }

  // finish l: reduce across the 16 column-lanes (butterfly leaves sum in all)
#pragma unroll
  for (int rt = 0; rt < 2; ++rt)
#pragma unroll
    for (int r = 0; r < 4; ++r) {
      float v = lsum[rt][r];
      v += __shfl_xor(v, 1);
      v += __shfl_xor(v, 2);
      v += __shfl_xor(v, 4);
      v += __shfl_xor(v, 8);
      lsum[rt][r] = v;
    }
  if (l15 == 0) {
#pragma unroll
    for (int rt = 0; rt < 2; ++rt)
#pragma unroll
      for (int r = 0; r < 4; ++r)
        linv_lds[srow + rt * 16 + quad * 4 + r] = 1.0f / lsum[rt][r];
  }
  __syncthreads();

  // epilogue: 32x32 C/D: col=l31, row=(e&3)+8*(e>>2)+4*half
#pragma unroll
  for (int rt2 = 0; rt2 < 2; ++rt2)
#pragma unroll
    for (int ct = 0; ct < 4; ++ct)
#pragma unroll
      for (int e = 0; e < 16; ++e) {
        int row = prow + rt2 * 32 + (e & 3) + 8 * (e >> 2) + 4 * half;
        int col = pcol + ct * 32 + l31;
        out[(size_t)(i0 + row) * G_ + g0 + col] = acc[rt2][ct][e] * linv_lds[row];
      }
}

extern "C" void kernel_launch(void* const* d_in, const int* in_sizes, int n_in,
                              void* d_out, int out_size, void* d_ws, size_t ws_size,
                              hipStream_t stream) {
  const float* expr = (const float*)d_in[0];  // [N][G]
  const float* enc  = (const float*)d_in[1];  // [N][D]
  const float* qual = (const float*)d_in[2];  // [N]
  float* out = (float*)d_out;                 // [N][G] fp32

  // workspace layout (requires ~34.7 MB):
  char* ws = (char*)d_ws;
  float* norms        = (float*)ws;                         // 32 KB
  float2* nq          = (float2*)(ws + 32768);              // 64 KB
  unsigned short* encb = (unsigned short*)(ws + 98304);     // 1 MB
  unsigned short* ET   = (unsigned short*)(ws + 1146880);   // 32 MB

  prep_kernel<<<dim3(N_ / 256), dim3(256), 0, stream>>>(enc, qual, norms, nq, encb);
  etrans_kernel<<<dim3(N_ / 64, G_ / 64), dim3(256), 0, stream>>>(expr, ET);
  fused_kernel<<<dim3((N_ / 128) * (G_ / 256)), dim3(256), 0, stream>>>(encb, norms, nq, ET, out);
}

// Round 2
// 559.816 us; speedup vs baseline: 1.6108x; 1.6108x over previous
//
#include <hip/hip_runtime.h>
#include <hip/hip_bf16.h>

// CellSmooth R2: split the fused kernel into
//   pk_kernel:   P[i][j] = exp(q_j - ||enc_i - enc_j||)  (bf16, 8192x8192)
//                + per-(1024-col-chunk) row sums  -> removes the 8x redundant
//                exp/sqrt recompute that dominated R1 (VALUBusy 52%, Mfma 17%)
//   gemm_kernel: out = (P @ ET^T) * (1/l)   -- m97-style 128x128 bf16 GEMM
//                with global_load_lds(16B) staging, 16x16x32 MFMA.
// Fallback to the verified R1 fused kernel if ws_size < ~162 MiB.

typedef __attribute__((ext_vector_type(8))) short bf16x8;
typedef __attribute__((ext_vector_type(4))) float f32x4;
typedef __attribute__((ext_vector_type(16))) float f32x16;

constexpr int N_ = 8192;
constexpr int G_ = 2048;
constexpr int D_ = 64;

__device__ __forceinline__ unsigned short f32_to_bf16(float f) {
  unsigned u = __builtin_bit_cast(unsigned, f);
  u = (u + 0x7FFFu + ((u >> 16) & 1u)) >> 16;  // RTNE
  return (unsigned short)u;
}
__device__ __forceinline__ float bf16_to_f32(unsigned short h) {
  unsigned u = ((unsigned)h) << 16;
  return __builtin_bit_cast(float, u);
}

typedef __attribute__((address_space(1))) const unsigned int glob_u32;
typedef __attribute__((address_space(3))) unsigned int lds_u32;
__device__ __forceinline__ void gload_lds16(const void* g, void* l) {
  __builtin_amdgcn_global_load_lds((glob_u32*)g, (lds_u32*)l, 16, 0, 0);
}

// --- prep: row norms + packed (norm, quality) + enc -> bf16 ---
__global__ void prep_kernel(const float* __restrict__ enc,
                            const float* __restrict__ quality,
                            float* __restrict__ norms,
                            float2* __restrict__ nq,
                            unsigned short* __restrict__ encb) {
  int row = blockIdx.x * blockDim.x + threadIdx.x;
  if (row >= N_) return;
  const float* r = enc + (size_t)row * D_;
  float n = 0.f;
#pragma unroll
  for (int k = 0; k < D_; k += 4) {
    float4 v = *(const float4*)(r + k);
    n += v.x * v.x + v.y * v.y + v.z * v.z + v.w * v.w;
    ushort4 h;
    h.x = f32_to_bf16(v.x); h.y = f32_to_bf16(v.y);
    h.z = f32_to_bf16(v.z); h.w = f32_to_bf16(v.w);
    *(ushort4*)(encb + (size_t)row * D_ + k) = h;
  }
  norms[row] = n;
  nq[row] = make_float2(n, quality[row]);
}

// --- expression [N][G] f32 -> ET [G][N] bf16 (transpose+convert) ---
__global__ void etrans_kernel(const float* __restrict__ E,
                              unsigned short* __restrict__ ET) {
  __shared__ __align__(16) unsigned short t[64 * 72];
  int j0 = blockIdx.x * 64;
  int g0 = blockIdx.y * 64;
  int tid = threadIdx.x;
#pragma unroll
  for (int it = 0; it < 4; ++it) {
    int r = it * 16 + (tid >> 4);
    int c4 = tid & 15;
    float4 v = *(const float4*)(E + (size_t)(j0 + r) * G_ + g0 + c4 * 4);
    t[(c4 * 4 + 0) * 72 + r] = f32_to_bf16(v.x);
    t[(c4 * 4 + 1) * 72 + r] = f32_to_bf16(v.y);
    t[(c4 * 4 + 2) * 72 + r] = f32_to_bf16(v.z);
    t[(c4 * 4 + 3) * 72 + r] = f32_to_bf16(v.w);
  }
  __syncthreads();
#pragma unroll
  for (int it = 0; it < 2; ++it) {
    int g = it * 32 + (tid >> 3);
    int ch = tid & 7;
    bf16x8 v = *(const bf16x8*)(&t[g * 72 + ch * 8]);
    *(bf16x8*)(ET + (size_t)(g0 + g) * N_ + j0 + ch * 8) = v;
  }
}

// --- pk: P[i][j] = bf16(exp(q_j - dist(i,j))), partial row sums ---
// grid (8 j-chunks of 1024, 128 i-tiles of 64); 256 thr = 4 waves,
// wave w owns i-rows [i0+16w, i0+16w+16).
__global__ __launch_bounds__(256)
void pk_kernel(const unsigned short* __restrict__ encb,
               const float* __restrict__ norms,
               const float2* __restrict__ nq,
               unsigned short* __restrict__ P,     // [N][N] bf16
               float* __restrict__ lpart) {        // [8][N]
  const int tid = threadIdx.x;
  const int wave = tid >> 6;
  const int lane = tid & 63;
  const int quad = lane >> 4;
  const int l15 = lane & 15;

  const int i0 = blockIdx.y * 64;
  const int jbase = blockIdx.x * 1024;
  const int irow_a = i0 + 16 * wave + l15;       // A-frag row
  const int irow_c = i0 + 16 * wave + quad * 4;  // C rows base (quad*4+r)

  bf16x8 afrag[2];
#pragma unroll
  for (int ks = 0; ks < 2; ++ks)
    afrag[ks] = *(const bf16x8*)(encb + (size_t)irow_a * 64 + ks * 32 + quad * 8);

  float ni[4];
#pragma unroll
  for (int r = 0; r < 4; ++r) ni[r] = norms[irow_c + r];

  float lsum[4] = {0.f, 0.f, 0.f, 0.f};

  for (int js = 0; js < 16; ++js) {
    const int j0j = jbase + js * 64;
#pragma unroll
    for (int jt = 0; jt < 4; ++jt) {
      const int jrow = j0j + jt * 16 + l15;
      bf16x8 b0 = *(const bf16x8*)(encb + (size_t)jrow * 64 + quad * 8);
      bf16x8 b1 = *(const bf16x8*)(encb + (size_t)jrow * 64 + 32 + quad * 8);
      float2 njq = nq[jrow];
      f32x4 s4 = {0.f, 0.f, 0.f, 0.f};
      s4 = __builtin_amdgcn_mfma_f32_16x16x32_bf16(afrag[0], b0, s4, 0, 0, 0);
      s4 = __builtin_amdgcn_mfma_f32_16x16x32_bf16(afrag[1], b1, s4, 0, 0, 0);
#pragma unroll
      for (int r = 0; r < 4; ++r) {
        float d2 = fmaxf(ni[r] + njq.x - 2.0f * s4[r], 0.f);
        float sc = njq.y - sqrtf(d2);
        if (irow_c + r == jrow) sc = njq.y;  // exact diagonal: d=0
        float p = __expf(sc);                // s in [-21, ~4.3]: no max shift
        unsigned short pb = f32_to_bf16(p);
        lsum[r] += bf16_to_f32(pb);          // l from rounded p: consistent
        P[(size_t)(irow_c + r) * N_ + jrow] = pb;
      }
    }
  }
  // reduce over the 16 column-lanes (l15); quads hold distinct rows
#pragma unroll
  for (int r = 0; r < 4; ++r) {
    float v = lsum[r];
    v += __shfl_xor(v, 1);
    v += __shfl_xor(v, 2);
    v += __shfl_xor(v, 4);
    v += __shfl_xor(v, 8);
    lsum[r] = v;
  }
  if (l15 == 0) {
#pragma unroll
    for (int r = 0; r < 4; ++r)
      lpart[(size_t)blockIdx.x * N_ + irow_c + r] = lsum[r];
  }
}

// --- inv: linv[i] = 1 / sum_c lpart[c][i] ---
__global__ void inv_kernel(const float* __restrict__ lpart,
                           float* __restrict__ linv) {
  int i = blockIdx.x * blockDim.x + threadIdx.x;
  if (i >= N_) return;
  float s = 0.f;
#pragma unroll
  for (int c = 0; c < 8; ++c) s += lpart[(size_t)c * N_ + i];
  linv[i] = 1.0f / s;
}

// --- gemm: out[i][g] = linv[i] * sum_j P[i][j] * ET[g][j] ---
// m97 structure: 128x128 tile, BK=64, global_load_lds(16B) staging,
// 4 waves in 2x2, each 64x64 via 4x4 of 16x16x32 MFMA.
__global__ __launch_bounds__(256, 2)
void gemm_kernel(const unsigned short* __restrict__ P,   // [N][N] bf16
                 const unsigned short* __restrict__ ET,  // [G][N] bf16
                 const float* __restrict__ linv,         // [N]
                 float* __restrict__ out) {              // [N][G] f32
  __shared__ __align__(16) unsigned short aT[128 * 64];  // [i][k]
  __shared__ __align__(16) unsigned short bT[128 * 64];  // [g][k]

  const int tid = threadIdx.x;
  const int wave = tid >> 6;
  const int lane = tid & 63;
  const int quad = lane >> 4;
  const int l15 = lane & 15;

  const int g0 = blockIdx.x * 128;
  const int i0 = blockIdx.y * 128;
  const int wrow = (wave >> 1) * 64;
  const int wcol = (wave & 1) * 64;

  const int srow = (tid >> 3);       // 0..31, staging row within sweep
  const int skb = (tid & 7) * 8;     // staging k element offset (16B)

  f32x4 acc[4][4];
#pragma unroll
  for (int a = 0; a < 4; ++a)
#pragma unroll
    for (int b = 0; b < 4; ++b) acc[a][b] = (f32x4){0.f, 0.f, 0.f, 0.f};

  for (int kk = 0; kk < N_; kk += 64) {
#pragma unroll
    for (int s = 0; s < 4; ++s) {
      int row = s * 32 + srow;
      gload_lds16(P + (size_t)(i0 + row) * N_ + kk + skb, &aT[row * 64 + skb]);
      gload_lds16(ET + (size_t)(g0 + row) * N_ + kk + skb, &bT[row * 64 + skb]);
    }
    __syncthreads();
#pragma unroll
    for (int ks = 0; ks < 2; ++ks) {
      bf16x8 aF[4], bF[4];
#pragma unroll
      for (int rt = 0; rt < 4; ++rt)
        aF[rt] = *(const bf16x8*)(&aT[(wrow + rt * 16 + l15) * 64 + ks * 32 + quad * 8]);
#pragma unroll
      for (int ct = 0; ct < 4; ++ct)
        bF[ct] = *(const bf16x8*)(&bT[(wcol + ct * 16 + l15) * 64 + ks * 32 + quad * 8]);
#pragma unroll
      for (int rt = 0; rt < 4; ++rt)
#pragma unroll
        for (int ct = 0; ct < 4; ++ct)
          acc[rt][ct] = __builtin_amdgcn_mfma_f32_16x16x32_bf16(aF[rt], bF[ct], acc[rt][ct], 0, 0, 0);
    }
    __syncthreads();
  }

  float li[4][4];
#pragma unroll
  for (int rt = 0; rt < 4; ++rt)
#pragma unroll
    for (int r = 0; r < 4; ++r)
      li[rt][r] = linv[i0 + wrow + rt * 16 + quad * 4 + r];

#pragma unroll
  for (int rt = 0; rt < 4; ++rt)
#pragma unroll
    for (int ct = 0; ct < 4; ++ct)
#pragma unroll
      for (int r = 0; r < 4; ++r) {
        int row = wrow + rt * 16 + quad * 4 + r;
        int col = wcol + ct * 16 + l15;
        out[(size_t)(i0 + row) * G_ + g0 + col] = acc[rt][ct][r] * li[rt][r];
      }
}

// ===================== R1 fused fallback (ws too small) =====================
__global__ __launch_bounds__(256, 2)
void fused_kernel(const unsigned short* __restrict__ encb,
                  const float* __restrict__ norms,
                  const float2* __restrict__ nq,
                  const unsigned short* __restrict__ ET,
                  float* __restrict__ out) {
  __shared__ __align__(16) unsigned short p_lds[128 * 72];
  __shared__ __align__(16) unsigned short e_lds[256 * 72];
  __shared__ float linv_lds[128];

  const int tid = threadIdx.x;
  const int wave = tid >> 6;
  const int lane = tid & 63;
  const int quad = lane >> 4;
  const int l15 = lane & 15;
  const int half = lane >> 5;
  const int l31 = lane & 31;

  const int gt = blockIdx.x & 7;
  const int it = blockIdx.x >> 3;
  const int i0 = it * 128;
  const int g0 = gt * 256;

  const int srow = 32 * wave;
  const int wr = wave >> 1, wc = wave & 1;
  const int prow = 64 * wr;
  const int pcol = 128 * wc;

  bf16x8 afrag[2][2];
#pragma unroll
  for (int rt = 0; rt < 2; ++rt)
#pragma unroll
    for (int ks = 0; ks < 2; ++ks)
      afrag[rt][ks] = *(const bf16x8*)(encb +
          (size_t)(i0 + srow + rt * 16 + l15) * 64 + ks * 32 + quad * 8);

  float ni[2][4];
#pragma unroll
  for (int rt = 0; rt < 2; ++rt)
#pragma unroll
    for (int r = 0; r < 4; ++r)
      ni[rt][r] = norms[i0 + srow + rt * 16 + quad * 4 + r];

  float lsum[2][4] = {};
  f32x16 acc[2][4];
#pragma unroll
  for (int a = 0; a < 2; ++a)
#pragma unroll
    for (int b = 0; b < 4; ++b)
#pragma unroll
      for (int e = 0; e < 16; ++e) acc[a][b][e] = 0.f;

  for (int j0j = 0; j0j < N_; j0j += 64) {
#pragma unroll
    for (int s = 0; s < 8; ++s) {
      int g = s * 32 + (tid >> 3);
      int ch = tid & 7;
      bf16x8 v = *(const bf16x8*)(ET + (size_t)(g0 + g) * N_ + j0j + ch * 8);
      *(bf16x8*)(&e_lds[g * 72 + ch * 8]) = v;
    }
#pragma unroll
    for (int jt = 0; jt < 4; ++jt) {
      const int jrow = j0j + jt * 16 + l15;
      bf16x8 b0 = *(const bf16x8*)(encb + (size_t)jrow * 64 + quad * 8);
      bf16x8 b1 = *(const bf16x8*)(encb + (size_t)jrow * 64 + 32 + quad * 8);
      float2 njq = nq[jrow];
#pragma unroll
      for (int rt = 0; rt < 2; ++rt) {
        f32x4 s4 = {0.f, 0.f, 0.f, 0.f};
        s4 = __builtin_amdgcn_mfma_f32_16x16x32_bf16(afrag[rt][0], b0, s4, 0, 0, 0);
        s4 = __builtin_amdgcn_mfma_f32_16x16x32_bf16(afrag[rt][1], b1, s4, 0, 0, 0);
#pragma unroll
        for (int r = 0; r < 4; ++r) {
          int i_loc = srow + rt * 16 + quad * 4 + r;
          float d2 = fmaxf(ni[rt][r] + njq.x - 2.0f * s4[r], 0.f);
          float sc = njq.y - sqrtf(d2);
          if (i0 + i_loc == jrow) sc = njq.y;
          float p = __expf(sc);
          unsigned short pb = f32_to_bf16(p);
          lsum[rt][r] += bf16_to_f32(pb);
          p_lds[i_loc * 72 + jt * 16 + l15] = pb;
        }
      }
    }
    __syncthreads();
#pragma unroll
    for (int ks = 0; ks < 4; ++ks) {
      bf16x8 pa0 = *(const bf16x8*)(&p_lds[(prow + l31) * 72 + ks * 16 + half * 8]);
      bf16x8 pa1 = *(const bf16x8*)(&p_lds[(prow + 32 + l31) * 72 + ks * 16 + half * 8]);
#pragma unroll
      for (int ct = 0; ct < 4; ++ct) {
        bf16x8 eb = *(const bf16x8*)(&e_lds[(pcol + ct * 32 + l31) * 72 + ks * 16 + half * 8]);
        acc[0][ct] = __builtin_amdgcn_mfma_f32_32x32x16_bf16(pa0, eb, acc[0][ct], 0, 0, 0);
        acc[1][ct] = __builtin_amdgcn_mfma_f32_32x32x16_bf16(pa1, eb, acc[1][ct], 0, 0, 0);
      }
    }
    __syncthreads();
  }

#pragma unroll
  for (int rt = 0; rt < 2; ++rt)
#pragma unroll
    for (int r = 0; r < 4; ++r) {
      float v = lsum[rt][r];
      v += __shfl_xor(v, 1);
      v += __shfl_xor(v, 2);
      v += __shfl_xor(v, 4);
      v += __shfl_xor(v, 8);
      lsum[rt][r] = v;
    }
  if (l15 == 0) {
#pragma unroll
    for (int rt = 0; rt < 2; ++rt)
#pragma unroll
      for (int r = 0; r < 4; ++r)
        linv_lds[srow + rt * 16 + quad * 4 + r] = 1.0f / lsum[rt][r];
  }
  __syncthreads();

#pragma unroll
  for (int rt2 = 0; rt2 < 2; ++rt2)
#pragma unroll
    for (int ct = 0; ct < 4; ++ct)
#pragma unroll
      for (int e = 0; e < 16; ++e) {
        int row = prow + rt2 * 32 + (e & 3) + 8 * (e >> 2) + 4 * half;
        int col = pcol + ct * 32 + l31;
        out[(size_t)(i0 + row) * G_ + g0 + col] = acc[rt2][ct][e] * linv_lds[row];
      }
}

extern "C" void kernel_launch(void* const* d_in, const int* in_sizes, int n_in,
                              void* d_out, int out_size, void* d_ws, size_t ws_size,
                              hipStream_t stream) {
  const float* expr = (const float*)d_in[0];  // [N][G]
  const float* enc  = (const float*)d_in[1];  // [N][D]
  const float* qual = (const float*)d_in[2];  // [N]
  float* out = (float*)d_out;                 // [N][G] f32

  char* ws = (char*)d_ws;
  // fast-path layout (~161.4 MiB)
  const size_t off_norms = 0;
  const size_t off_nq    = 32768;
  const size_t off_lpart = 98304;                     // 8*8192*4 = 256 KB
  const size_t off_linv  = 360448;
  const size_t off_encb  = 393216;                    // 1 MB
  const size_t off_ET    = 1441792;                   // 32 MB
  const size_t off_P     = 34996224;                  // 128 MB
  const size_t need      = off_P + (size_t)N_ * N_ * 2;  // 169,213,952

  if (ws_size >= need) {
    float* norms         = (float*)(ws + off_norms);
    float2* nqp          = (float2*)(ws + off_nq);
    float* lpart         = (float*)(ws + off_lpart);
    float* linv          = (float*)(ws + off_linv);
    unsigned short* encb = (unsigned short*)(ws + off_encb);
    unsigned short* ET   = (unsigned short*)(ws + off_ET);
    unsigned short* P    = (unsigned short*)(ws + off_P);

    prep_kernel<<<dim3(N_ / 256), dim3(256), 0, stream>>>(enc, qual, norms, nqp, encb);
    etrans_kernel<<<dim3(N_ / 64, G_ / 64), dim3(256), 0, stream>>>(expr, ET);
    pk_kernel<<<dim3(8, N_ / 64), dim3(256), 0, stream>>>(encb, norms, nqp, P, lpart);
    inv_kernel<<<dim3(N_ / 256), dim3(256), 0, stream>>>(lpart, linv);
    gemm_kernel<<<dim3(G_ / 128, N_ / 128), dim3(256), 0, stream>>>(P, ET, linv, out);
  } else {
    // R1 fused fallback (needs ~34.7 MB)
    float* norms         = (float*)ws;
    float2* nqp          = (float2*)(ws + 32768);
    unsigned short* encb = (unsigned short*)(ws + 98304);
    unsigned short* ET   = (unsigned short*)(ws + 1146880);
    prep_kernel<<<dim3(N_ / 256), dim3(256), 0, stream>>>(enc, qual, norms, nqp, encb);
    etrans_kernel<<<dim3(N_ / 64, G_ / 64), dim3(256), 0, stream>>>(expr, ET);
    fused_kernel<<<dim3((N_ / 128) * (G_ / 256)), dim3(256), 0, stream>>>(encb, norms, nqp, ET, out);
  }
}

// Round 3
// 450.041 us; speedup vs baseline: 2.0038x; 1.2439x over previous
//
#include <hip/hip_runtime.h>
#include <hip/hip_bf16.h>

// CellSmooth R3:
//  - gemm_kernel: 256x128 block tile (wave tile 128x64), XOR-swizzled LDS
//    chunks to kill the 16-way bank conflicts R2 exposed (1.0e8 conflicts:
//    row stride 128 B == 32 banks made bank independent of row).  Swizzle is
//    applied on the *global source* chunk so global_load_lds's lane-contiguous
//    LDS destination constraint is respected.
//  - pk_kernel: P tile bounced through LDS so global P writes are 16 B/lane
//    coalesced row segments instead of 2 B scalar scatter.
// Fallback to the verified R1 fused kernel if ws_size < ~162 MiB.

typedef __attribute__((ext_vector_type(8))) short bf16x8;
typedef __attribute__((ext_vector_type(4))) float f32x4;
typedef __attribute__((ext_vector_type(16))) float f32x16;

constexpr int N_ = 8192;
constexpr int G_ = 2048;
constexpr int D_ = 64;

__device__ __forceinline__ unsigned short f32_to_bf16(float f) {
  unsigned u = __builtin_bit_cast(unsigned, f);
  u = (u + 0x7FFFu + ((u >> 16) & 1u)) >> 16;  // RTNE
  return (unsigned short)u;
}
__device__ __forceinline__ float bf16_to_f32(unsigned short h) {
  unsigned u = ((unsigned)h) << 16;
  return __builtin_bit_cast(float, u);
}

typedef __attribute__((address_space(1))) const unsigned int glob_u32;
typedef __attribute__((address_space(3))) unsigned int lds_u32;
__device__ __forceinline__ void gload_lds16(const void* g, void* l) {
  __builtin_amdgcn_global_load_lds((glob_u32*)g, (lds_u32*)l, 16, 0, 0);
}

// --- prep: row norms + packed (norm, quality) + enc -> bf16 ---
__global__ void prep_kernel(const float* __restrict__ enc,
                            const float* __restrict__ quality,
                            float* __restrict__ norms,
                            float2* __restrict__ nq,
                            unsigned short* __restrict__ encb) {
  int row = blockIdx.x * blockDim.x + threadIdx.x;
  if (row >= N_) return;
  const float* r = enc + (size_t)row * D_;
  float n = 0.f;
#pragma unroll
  for (int k = 0; k < D_; k += 4) {
    float4 v = *(const float4*)(r + k);
    n += v.x * v.x + v.y * v.y + v.z * v.z + v.w * v.w;
    ushort4 h;
    h.x = f32_to_bf16(v.x); h.y = f32_to_bf16(v.y);
    h.z = f32_to_bf16(v.z); h.w = f32_to_bf16(v.w);
    *(ushort4*)(encb + (size_t)row * D_ + k) = h;
  }
  norms[row] = n;
  nq[row] = make_float2(n, quality[row]);
}

// --- expression [N][G] f32 -> ET [G][N] bf16 (transpose+convert) ---
__global__ void etrans_kernel(const float* __restrict__ E,
                              unsigned short* __restrict__ ET) {
  __shared__ __align__(16) unsigned short t[64 * 72];
  int j0 = blockIdx.x * 64;
  int g0 = blockIdx.y * 64;
  int tid = threadIdx.x;
#pragma unroll
  for (int it = 0; it < 4; ++it) {
    int r = it * 16 + (tid >> 4);
    int c4 = tid & 15;
    float4 v = *(const float4*)(E + (size_t)(j0 + r) * G_ + g0 + c4 * 4);
    t[(c4 * 4 + 0) * 72 + r] = f32_to_bf16(v.x);
    t[(c4 * 4 + 1) * 72 + r] = f32_to_bf16(v.y);
    t[(c4 * 4 + 2) * 72 + r] = f32_to_bf16(v.z);
    t[(c4 * 4 + 3) * 72 + r] = f32_to_bf16(v.w);
  }
  __syncthreads();
#pragma unroll
  for (int it = 0; it < 2; ++it) {
    int g = it * 32 + (tid >> 3);
    int ch = tid & 7;
    bf16x8 v = *(const bf16x8*)(&t[g * 72 + ch * 8]);
    *(bf16x8*)(ET + (size_t)(g0 + g) * N_ + j0 + ch * 8) = v;
  }
}

// --- pk: P[i][j] = bf16(exp(q_j - dist(i,j))), partial row sums ---
// grid (8 j-chunks of 1024, 128 i-tiles of 64); 256 thr = 4 waves,
// wave w owns i-rows [i0+16w, i0+16w+16).  P writes coalesced via LDS bounce.
__global__ __launch_bounds__(256)
void pk_kernel(const unsigned short* __restrict__ encb,
               const float* __restrict__ norms,
               const float2* __restrict__ nq,
               unsigned short* __restrict__ P,     // [N][N] bf16
               float* __restrict__ lpart) {        // [8][N]
  __shared__ __align__(16) unsigned short p_lds[64 * 72];

  const int tid = threadIdx.x;
  const int wave = tid >> 6;
  const int lane = tid & 63;
  const int quad = lane >> 4;
  const int l15 = lane & 15;

  const int i0 = blockIdx.y * 64;
  const int jbase = blockIdx.x * 1024;
  const int irow_a = i0 + 16 * wave + l15;       // A-frag row
  const int iloc_c = 16 * wave + quad * 4;       // local C rows base
  const int irow_c = i0 + iloc_c;

  // store-phase lane mapping: 16 rows/wave, 4 lanes/row, 2 chunks/lane
  const int srow_loc = 16 * wave + (lane >> 2);

  bf16x8 afrag[2];
#pragma unroll
  for (int ks = 0; ks < 2; ++ks)
    afrag[ks] = *(const bf16x8*)(encb + (size_t)irow_a * 64 + ks * 32 + quad * 8);

  float ni[4];
#pragma unroll
  for (int r = 0; r < 4; ++r) ni[r] = norms[irow_c + r];

  float lsum[4] = {0.f, 0.f, 0.f, 0.f};

  for (int js = 0; js < 16; ++js) {
    const int j0j = jbase + js * 64;
#pragma unroll
    for (int jt = 0; jt < 4; ++jt) {
      const int jrow = j0j + jt * 16 + l15;
      bf16x8 b0 = *(const bf16x8*)(encb + (size_t)jrow * 64 + quad * 8);
      bf16x8 b1 = *(const bf16x8*)(encb + (size_t)jrow * 64 + 32 + quad * 8);
      float2 njq = nq[jrow];
      f32x4 s4 = {0.f, 0.f, 0.f, 0.f};
      s4 = __builtin_amdgcn_mfma_f32_16x16x32_bf16(afrag[0], b0, s4, 0, 0, 0);
      s4 = __builtin_amdgcn_mfma_f32_16x16x32_bf16(afrag[1], b1, s4, 0, 0, 0);
#pragma unroll
      for (int r = 0; r < 4; ++r) {
        float d2 = fmaxf(ni[r] + njq.x - 2.0f * s4[r], 0.f);
        float sc = njq.y - sqrtf(d2);
        if (irow_c + r == jrow) sc = njq.y;  // exact diagonal: d=0
        float p = __expf(sc);                // s in [-21, ~4.3]: no max shift
        unsigned short pb = f32_to_bf16(p);
        lsum[r] += bf16_to_f32(pb);          // l from rounded p: consistent
        p_lds[(iloc_c + r) * 72 + jt * 16 + l15] = pb;
      }
    }
    __syncthreads();
    // coalesced store: each lane two 16B chunks of its row
#pragma unroll
    for (int k = 0; k < 2; ++k) {
      int c = (lane & 3) + k * 4;  // chunk 0..7
      bf16x8 v = *(const bf16x8*)(&p_lds[srow_loc * 72 + c * 8]);
      *(bf16x8*)(P + (size_t)(i0 + srow_loc) * N_ + j0j + c * 8) = v;
    }
    __syncthreads();
  }
  // reduce over the 16 column-lanes (l15); quads hold distinct rows
#pragma unroll
  for (int r = 0; r < 4; ++r) {
    float v = lsum[r];
    v += __shfl_xor(v, 1);
    v += __shfl_xor(v, 2);
    v += __shfl_xor(v, 4);
    v += __shfl_xor(v, 8);
    lsum[r] = v;
  }
  if (l15 == 0) {
#pragma unroll
    for (int r = 0; r < 4; ++r)
      lpart[(size_t)blockIdx.x * N_ + irow_c + r] = lsum[r];
  }
}

// --- inv: linv[i] = 1 / sum_c lpart[c][i] ---
__global__ void inv_kernel(const float* __restrict__ lpart,
                           float* __restrict__ linv) {
  int i = blockIdx.x * blockDim.x + threadIdx.x;
  if (i >= N_) return;
  float s = 0.f;
#pragma unroll
  for (int c = 0; c < 8; ++c) s += lpart[(size_t)c * N_ + i];
  linv[i] = 1.0f / s;
}

// --- gemm: out[i][g] = linv[i] * sum_j P[i][j] * ET[g][j] ---
// 256x128 block tile, BK=64, XOR-swizzled LDS chunks (conflict-free frag
// reads), wave tile 128x64 (8x4 of 16x16x32 MFMA), 2 blocks/CU.
__global__ __launch_bounds__(256, 2)
void gemm_kernel(const unsigned short* __restrict__ P,   // [N][N] bf16
                 const unsigned short* __restrict__ ET,  // [G][N] bf16
                 const float* __restrict__ linv,         // [N]
                 float* __restrict__ out) {              // [N][G] f32
  __shared__ __align__(16) unsigned short aT[256 * 64];  // [i][k] swizzled
  __shared__ __align__(16) unsigned short bT[128 * 64];  // [g][k] swizzled

  const int tid = threadIdx.x;
  const int wave = tid >> 6;
  const int lane = tid & 63;
  const int quad = lane >> 4;
  const int l15 = lane & 15;

  const int g0 = blockIdx.x * 128;
  const int i0 = blockIdx.y * 256;
  const int wrow = (wave >> 1) * 128;
  const int wcol = (wave & 1) * 64;

  const int strow = tid >> 3;     // 0..31 staging row within sweep
  const int stc = tid & 7;        // staging chunk (LDS dest, lane-contiguous)

  f32x4 acc[8][4];
#pragma unroll
  for (int a = 0; a < 8; ++a)
#pragma unroll
    for (int b = 0; b < 4; ++b) acc[a][b] = (f32x4){0.f, 0.f, 0.f, 0.f};

  for (int kk = 0; kk < N_; kk += 64) {
    // A: 256 rows; LDS[row][c] = global chunk (c ^ (row&7))
#pragma unroll
    for (int s = 0; s < 8; ++s) {
      int row = s * 32 + strow;
      int csrc = stc ^ (row & 7);
      gload_lds16(P + (size_t)(i0 + row) * N_ + kk + csrc * 8,
                  &aT[row * 64 + stc * 8]);
    }
    // B: 128 rows
#pragma unroll
    for (int s = 0; s < 4; ++s) {
      int row = s * 32 + strow;
      int csrc = stc ^ (row & 7);
      gload_lds16(ET + (size_t)(g0 + row) * N_ + kk + csrc * 8,
                  &bT[row * 64 + stc * 8]);
    }
    __syncthreads();
#pragma unroll
    for (int ks = 0; ks < 2; ++ks) {
      const int swzk = ((ks * 4 + quad) ^ (l15 & 7)) * 8;
      bf16x8 bF[4];
#pragma unroll
      for (int ct = 0; ct < 4; ++ct)
        bF[ct] = *(const bf16x8*)(&bT[(wcol + ct * 16 + l15) * 64 + swzk]);
#pragma unroll
      for (int rt = 0; rt < 8; ++rt) {
        bf16x8 aF = *(const bf16x8*)(&aT[(wrow + rt * 16 + l15) * 64 + swzk]);
#pragma unroll
        for (int ct = 0; ct < 4; ++ct)
          acc[rt][ct] = __builtin_amdgcn_mfma_f32_16x16x32_bf16(aF, bF[ct], acc[rt][ct], 0, 0, 0);
      }
    }
    __syncthreads();
  }

  float li[8];
#pragma unroll
  for (int rt = 0; rt < 8; ++rt) {
    // li depends on r too; load per (rt,r) below via 4 separate values
    li[rt] = 0.f;  // placeholder, real loads below
  }
#pragma unroll
  for (int rt = 0; rt < 8; ++rt) {
    float lir[4];
#pragma unroll
    for (int r = 0; r < 4; ++r)
      lir[r] = linv[i0 + wrow + rt * 16 + quad * 4 + r];
#pragma unroll
    for (int ct = 0; ct < 4; ++ct)
#pragma unroll
      for (int r = 0; r < 4; ++r) {
        int row = wrow + rt * 16 + quad * 4 + r;
        int col = wcol + ct * 16 + l15;
        out[(size_t)(i0 + row) * G_ + g0 + col] = acc[rt][ct][r] * lir[r];
      }
  }
}

// ===================== R1 fused fallback (ws too small) =====================
__global__ __launch_bounds__(256, 2)
void fused_kernel(const unsigned short* __restrict__ encb,
                  const float* __restrict__ norms,
                  const float2* __restrict__ nq,
                  const unsigned short* __restrict__ ET,
                  float* __restrict__ out) {
  __shared__ __align__(16) unsigned short p_lds[128 * 72];
  __shared__ __align__(16) unsigned short e_lds[256 * 72];
  __shared__ float linv_lds[128];

  const int tid = threadIdx.x;
  const int wave = tid >> 6;
  const int lane = tid & 63;
  const int quad = lane >> 4;
  const int l15 = lane & 15;
  const int half = lane >> 5;
  const int l31 = lane & 31;

  const int gt = blockIdx.x & 7;
  const int it = blockIdx.x >> 3;
  const int i0 = it * 128;
  const int g0 = gt * 256;

  const int srow = 32 * wave;
  const int wr = wave >> 1, wc = wave & 1;
  const int prow = 64 * wr;
  const int pcol = 128 * wc;

  bf16x8 afrag[2][2];
#pragma unroll
  for (int rt = 0; rt < 2; ++rt)
#pragma unroll
    for (int ks = 0; ks < 2; ++ks)
      afrag[rt][ks] = *(const bf16x8*)(encb +
          (size_t)(i0 + srow + rt * 16 + l15) * 64 + ks * 32 + quad * 8);

  float ni[2][4];
#pragma unroll
  for (int rt = 0; rt < 2; ++rt)
#pragma unroll
    for (int r = 0; r < 4; ++r)
      ni[rt][r] = norms[i0 + srow + rt * 16 + quad * 4 + r];

  float lsum[2][4] = {};
  f32x16 acc[2][4];
#pragma unroll
  for (int a = 0; a < 2; ++a)
#pragma unroll
    for (int b = 0; b < 4; ++b)
#pragma unroll
      for (int e = 0; e < 16; ++e) acc[a][b][e] = 0.f;

  for (int j0j = 0; j0j < N_; j0j += 64) {
#pragma unroll
    for (int s = 0; s < 8; ++s) {
      int g = s * 32 + (tid >> 3);
      int ch = tid & 7;
      bf16x8 v = *(const bf16x8*)(ET + (size_t)(g0 + g) * N_ + j0j + ch * 8);
      *(bf16x8*)(&e_lds[g * 72 + ch * 8]) = v;
    }
#pragma unroll
    for (int jt = 0; jt < 4; ++jt) {
      const int jrow = j0j + jt * 16 + l15;
      bf16x8 b0 = *(const bf16x8*)(encb + (size_t)jrow * 64 + quad * 8);
      bf16x8 b1 = *(const bf16x8*)(encb + (size_t)jrow * 64 + 32 + quad * 8);
      float2 njq = nq[jrow];
#pragma unroll
      for (int rt = 0; rt < 2; ++rt) {
        f32x4 s4 = {0.f, 0.f, 0.f, 0.f};
        s4 = __builtin_amdgcn_mfma_f32_16x16x32_bf16(afrag[rt][0], b0, s4, 0, 0, 0);
        s4 = __builtin_amdgcn_mfma_f32_16x16x32_bf16(afrag[rt][1], b1, s4, 0, 0, 0);
#pragma unroll
        for (int r = 0; r < 4; ++r) {
          int i_loc = srow + rt * 16 + quad * 4 + r;
          float d2 = fmaxf(ni[rt][r] + njq.x - 2.0f * s4[r], 0.f);
          float sc = njq.y - sqrtf(d2);
          if (i0 + i_loc == jrow) sc = njq.y;
          float p = __expf(sc);
          unsigned short pb = f32_to_bf16(p);
          lsum[rt][r] += bf16_to_f32(pb);
          p_lds[i_loc * 72 + jt * 16 + l15] = pb;
        }
      }
    }
    __syncthreads();
#pragma unroll
    for (int ks = 0; ks < 4; ++ks) {
      bf16x8 pa0 = *(const bf16x8*)(&p_lds[(prow + l31) * 72 + ks * 16 + half * 8]);
      bf16x8 pa1 = *(const bf16x8*)(&p_lds[(prow + 32 + l31) * 72 + ks * 16 + half * 8]);
#pragma unroll
      for (int ct = 0; ct < 4; ++ct) {
        bf16x8 eb = *(const bf16x8*)(&e_lds[(pcol + ct * 32 + l31) * 72 + ks * 16 + half * 8]);
        acc[0][ct] = __builtin_amdgcn_mfma_f32_32x32x16_bf16(pa0, eb, acc[0][ct], 0, 0, 0);
        acc[1][ct] = __builtin_amdgcn_mfma_f32_32x32x16_bf16(pa1, eb, acc[1][ct], 0, 0, 0);
      }
    }
    __syncthreads();
  }

#pragma unroll
  for (int rt = 0; rt < 2; ++rt)
#pragma unroll
    for (int r = 0; r < 4; ++r) {
      float v = lsum[rt][r];
      v += __shfl_xor(v, 1);
      v += __shfl_xor(v, 2);
      v += __shfl_xor(v, 4);
      v += __shfl_xor(v, 8);
      lsum[rt][r] = v;
    }
  if (l15 == 0) {
#pragma unroll
    for (int rt = 0; rt < 2; ++rt)
#pragma unroll
      for (int r = 0; r < 4; ++r)
        linv_lds[srow + rt * 16 + quad * 4 + r] = 1.0f / lsum[rt][r];
  }
  __syncthreads();

#pragma unroll
  for (int rt2 = 0; rt2 < 2; ++rt2)
#pragma unroll
    for (int ct = 0; ct < 4; ++ct)
#pragma unroll
      for (int e = 0; e < 16; ++e) {
        int row = prow + rt2 * 32 + (e & 3) + 8 * (e >> 2) + 4 * half;
        int col = pcol + ct * 32 + l31;
        out[(size_t)(i0 + row) * G_ + g0 + col] = acc[rt2][ct][e] * linv_lds[row];
      }
}

extern "C" void kernel_launch(void* const* d_in, const int* in_sizes, int n_in,
                              void* d_out, int out_size, void* d_ws, size_t ws_size,
                              hipStream_t stream) {
  const float* expr = (const float*)d_in[0];  // [N][G]
  const float* enc  = (const float*)d_in[1];  // [N][D]
  const float* qual = (const float*)d_in[2];  // [N]
  float* out = (float*)d_out;                 // [N][G] f32

  char* ws = (char*)d_ws;
  const size_t off_norms = 0;
  const size_t off_nq    = 32768;
  const size_t off_lpart = 98304;                     // 8*8192*4 = 256 KB
  const size_t off_linv  = 360448;
  const size_t off_encb  = 393216;                    // 1 MB
  const size_t off_ET    = 1441792;                   // 32 MB
  const size_t off_P     = 34996224;                  // 128 MB
  const size_t need      = off_P + (size_t)N_ * N_ * 2;  // ~161.4 MiB

  if (ws_size >= need) {
    float* norms         = (float*)(ws + off_norms);
    float2* nqp          = (float2*)(ws + off_nq);
    float* lpart         = (float*)(ws + off_lpart);
    float* linv          = (float*)(ws + off_linv);
    unsigned short* encb = (unsigned short*)(ws + off_encb);
    unsigned short* ET   = (unsigned short*)(ws + off_ET);
    unsigned short* P    = (unsigned short*)(ws + off_P);

    prep_kernel<<<dim3(N_ / 256), dim3(256), 0, stream>>>(enc, qual, norms, nqp, encb);
    etrans_kernel<<<dim3(N_ / 64, G_ / 64), dim3(256), 0, stream>>>(expr, ET);
    pk_kernel<<<dim3(8, N_ / 64), dim3(256), 0, stream>>>(encb, norms, nqp, P, lpart);
    inv_kernel<<<dim3(N_ / 256), dim3(256), 0, stream>>>(lpart, linv);
    gemm_kernel<<<dim3(G_ / 128, N_ / 256), dim3(256), 0, stream>>>(P, ET, linv, out);
  } else {
    float* norms         = (float*)ws;
    float2* nqp          = (float2*)(ws + 32768);
    unsigned short* encb = (unsigned short*)(ws + 98304);
    unsigned short* ET   = (unsigned short*)(ws + 1146880);
    prep_kernel<<<dim3(N_ / 256), dim3(256), 0, stream>>>(enc, qual, norms, nqp, encb);
    etrans_kernel<<<dim3(N_ / 64, G_ / 64), dim3(256), 0, stream>>>(expr, ET);
    fused_kernel<<<dim3((N_ / 128) * (G_ / 256)), dim3(256), 0, stream>>>(encb, norms, nqp, ET, out);
  }
}